// Round 7
// baseline (253.378 us; speedup 1.0000x reference)
//
#include <hip/hip_runtime.h>

// DistributionTracker: per-label scatter-add of [count | sum(X) | sum(X^2)]
// X: (N, 128) fp32, labels: (N,) int32, out: (classes, 257) fp32 row-major.
//
// Round-7: full sort-by-class, then atomic-free register accumulation.
//   k1 hist   : per-block LDS histogram -> partials hp[block][class]
//               (int4 label loads); no global atomics, no ws pre-zero
//   k2 prefix : column-sum partials (coalesced, L2-hot) + Hillis-Steele scan
//   k3 scatter: per-block LDS hist + cursor base, row indices sorted by class
//   k4 accum  : ONE 512-thread block per class (8 waves = 8 class-segments,
//               ~31 waves/CU for deep DRAM request queues); lane owns cols
//               {2l,2l+1}; one dwordx2 (512B/wave) load per row; 8 unroll-slot
//               register accumulators; LDS cross-wave reduce; PLAIN full-row
//               stores (no global atomics, no d_out pre-zero needed).
// Fallback: round-1 ballot-scan kernel (correct, slow) if ws too small.

constexpr int DIM    = 128;
constexpr int ROWLEN = 2 * DIM + 1;    // 257

constexpr int HIST_B = 256;
constexpr int HIST_T = 256;

// ---------------------------------------------------------------- binning --
__global__ __launch_bounds__(HIST_T)
void hist_kernel(const int* __restrict__ labels, int N, int classes,
                 unsigned* __restrict__ hist_part)   // [HIST_B][1024]
{
    __shared__ unsigned lh[1024];
    for (int i = threadIdx.x; i < 1024; i += HIST_T) lh[i] = 0;
    __syncthreads();

    const int gtid = blockIdx.x * HIST_T + threadIdx.x;
    const int gstr = HIST_B * HIST_T;
    const int N4   = N >> 2;
    const int4* l4 = (const int4*)labels;
    for (int i = gtid; i < N4; i += gstr) {
        const int4 v = l4[i];
        if ((unsigned)v.x < (unsigned)classes) atomicAdd(&lh[v.x], 1u);
        if ((unsigned)v.y < (unsigned)classes) atomicAdd(&lh[v.y], 1u);
        if ((unsigned)v.z < (unsigned)classes) atomicAdd(&lh[v.z], 1u);
        if ((unsigned)v.w < (unsigned)classes) atomicAdd(&lh[v.w], 1u);
    }
    for (int i = (N4 << 2) + gtid; i < N; i += gstr) {
        const unsigned l = (unsigned)labels[i];
        if (l < (unsigned)classes) atomicAdd(&lh[l], 1u);
    }
    __syncthreads();
    unsigned* hp = hist_part + (size_t)blockIdx.x * 1024;
    for (int i = threadIdx.x; i < 1024; i += HIST_T) hp[i] = lh[i];
}

__global__ __launch_bounds__(1024)
void prefix_kernel(const unsigned* __restrict__ hist_part,
                   unsigned* __restrict__ off,
                   unsigned* __restrict__ cursor, int classes)
{
    __shared__ unsigned s[1024];
    const int tid = threadIdx.x;
    unsigned a0 = 0, a1 = 0, a2 = 0, a3 = 0;
    for (int b = 0; b < HIST_B; b += 4) {               // coalesced across tid
        a0 += hist_part[(b + 0) * 1024 + tid];
        a1 += hist_part[(b + 1) * 1024 + tid];
        a2 += hist_part[(b + 2) * 1024 + tid];
        a3 += hist_part[(b + 3) * 1024 + tid];
    }
    s[tid] = (tid < classes) ? (a0 + a1 + a2 + a3) : 0u;
    __syncthreads();
    for (int d = 1; d < 1024; d <<= 1) {
        unsigned v = (tid >= d) ? s[tid - d] : 0u;
        __syncthreads();
        s[tid] += v;
        __syncthreads();
    }
    if (tid == 0) { off[0] = 0; cursor[0] = 0; }
    if (tid < classes) {
        off[tid + 1] = s[tid];
        if (tid > 0) cursor[tid] = s[tid - 1];
    }
}

constexpr int SCAT_T  = 256;
constexpr int SCAT_IT = 16;            // 4096 rows per block

__global__ __launch_bounds__(SCAT_T)
void scatter_kernel(const int* __restrict__ labels, int N, int classes,
                    unsigned* __restrict__ cursor,
                    unsigned* __restrict__ idx)
{
    __shared__ unsigned lh[1024], lbase[1024];
    const int tid  = threadIdx.x;
    const int tile = blockIdx.x * (SCAT_T * SCAT_IT);
    for (int i = tid; i < 1024; i += SCAT_T) lh[i] = 0;
    __syncthreads();

    int lab[SCAT_IT];
#pragma unroll
    for (int k = 0; k < SCAT_IT; ++k) {
        const int row = tile + k * SCAT_T + tid;
        lab[k] = -1;
        if (row < N) {
            const unsigned l = (unsigned)labels[row];
            if (l < (unsigned)classes) { lab[k] = (int)l; atomicAdd(&lh[l], 1u); }
        }
    }
    __syncthreads();
    for (int c = tid; c < classes; c += SCAT_T) {
        if (lh[c]) lbase[c] = atomicAdd(&cursor[c], lh[c]);
        lh[c] = 0;
    }
    __syncthreads();
#pragma unroll
    for (int k = 0; k < SCAT_IT; ++k) {
        if (lab[k] >= 0) {
            const unsigned l   = (unsigned)lab[k];
            const unsigned row = (unsigned)(tile + k * SCAT_T + tid);
            idx[lbase[l] + atomicAdd(&lh[l], 1u)] = row;
        }
    }
}

// ------------------------------------------------------------- accumulate --
constexpr int SPLIT = 8;               // waves per class (all in one block)
constexpr int AT    = 64 * SPLIT;      // 512 threads
constexpr int U     = 8;               // rows in flight per wave

__global__ __launch_bounds__(AT, 8)
void accum_kernel(const float* __restrict__ X,
                  const unsigned* __restrict__ gidx,
                  const unsigned* __restrict__ off,
                  float* __restrict__ out)
{
    const int c = blockIdx.x;
    const unsigned s   = off[c];
    const unsigned cnt = off[c + 1] - s;

    const int tid  = threadIdx.x;
    const int lane = tid & 63;
    const int wid  = tid >> 6;

    const unsigned s_h = s + (unsigned)(((unsigned long long)cnt * wid) / SPLIT);
    const unsigned e_h = s + (unsigned)(((unsigned long long)cnt * (wid + 1)) / SPLIT);

    float2 m[U], q[U];
#pragma unroll
    for (int u = 0; u < U; ++u) {
        m[u].x = m[u].y = 0.0f; q[u].x = q[u].y = 0.0f;
    }

    unsigned p = s_h;
    for (; p + U <= e_h; p += U) {
        const float2* Xr[U];
#pragma unroll
        for (int u = 0; u < U; ++u) {
            const unsigned r = __builtin_amdgcn_readfirstlane(gidx[p + u]);
            Xr[u] = (const float2*)(X + (size_t)r * DIM);
        }
#pragma unroll
        for (int u = 0; u < U; ++u) {
            const float2 x = Xr[u][lane];           // cols {2l, 2l+1}, 512B/wave
            m[u].x += x.x;                   m[u].y += x.y;
            q[u].x = fmaf(x.x, x.x, q[u].x); q[u].y = fmaf(x.y, x.y, q[u].y);
        }
    }
    for (; p < e_h; ++p) {
        const unsigned r = __builtin_amdgcn_readfirstlane(gidx[p]);
        const float2 x = ((const float2*)(X + (size_t)r * DIM))[lane];
        m[0].x += x.x;                   m[0].y += x.y;
        q[0].x = fmaf(x.x, x.x, q[0].x); q[0].y = fmaf(x.y, x.y, q[0].y);
    }

#pragma unroll
    for (int u = 1; u < U; ++u) {
        m[0].x += m[u].x; m[0].y += m[u].y;
        q[0].x += q[u].x; q[0].y += q[u].y;
    }

    // cross-wave reduce in LDS, then plain full-row stores (no atomics)
    __shared__ float2 red_m[SPLIT][64];
    __shared__ float2 red_q[SPLIT][64];
    red_m[wid][lane] = m[0];
    red_q[wid][lane] = q[0];
    __syncthreads();

    float* po = out + (size_t)c * ROWLEN;
    if (tid < 64) {
        float2 a = {0.0f, 0.0f};
#pragma unroll
        for (int w = 0; w < SPLIT; ++w) {
            a.x += red_m[w][tid].x; a.y += red_m[w][tid].y;
        }
        po[1 + 2 * tid] = a.x;
        po[2 + 2 * tid] = a.y;
    } else if (tid < 128) {
        const int l = tid - 64;
        float2 a = {0.0f, 0.0f};
#pragma unroll
        for (int w = 0; w < SPLIT; ++w) {
            a.x += red_q[w][l].x; a.y += red_q[w][l].y;
        }
        po[129 + 2 * l] = a.x;
        po[130 + 2 * l] = a.y;
    } else if (tid == 128) {
        po[0] = (float)cnt;
    }
}

// ---------------------------------------------------- fallback (round 1) ---
constexpr int FB_T = 512;
constexpr int FB_W = FB_T / 64;
constexpr int FB_CG = 63;

__global__ __launch_bounds__(FB_T, 2)
void fb_kernel(const float* __restrict__ X, const int* __restrict__ labels,
               float* __restrict__ out, int N, int classes, int rpc)
{
    __shared__ float part[FB_CG * ROWLEN];
    const int tid = threadIdx.x, lane = tid & 63, wid = tid >> 6;
    const int gbase = blockIdx.y * FB_CG;
    for (int i = tid; i < FB_CG * ROWLEN; i += FB_T) part[i] = 0.0f;
    __syncthreads();
    const long long row0 = (long long)blockIdx.x * rpc;
    int rows = rpc;
    if (row0 + rows > N) rows = (int)((long long)N - row0);
    for (int base = wid * 64; base < rows; base += FB_W * 64) {
        const int nb = min(64, rows - base);
        int lab = -1;
        if (lane < nb) lab = labels[row0 + base + lane];
        const int lc = lab - gbase;
        const bool in = (lab >= 0) && (lc >= 0) && (lc < FB_CG) && (lab < classes);
        unsigned long long mask = __ballot(in);
        while (mask) {
            const int j = __ffsll((long long)mask) - 1;
            mask &= mask - 1;
            const int cc = __shfl(lc, j);
            const size_t ridx = (size_t)(row0 + base + j) * DIM;
            const float x0 = X[ridx + lane];
            const float x1 = X[ridx + lane + 64];
            float* pp = &part[cc * ROWLEN];
            unsafeAtomicAdd(&pp[1 + lane], x0);
            unsafeAtomicAdd(&pp[65 + lane], x1);
            unsafeAtomicAdd(&pp[129 + lane], x0 * x0);
            unsafeAtomicAdd(&pp[193 + lane], x1 * x1);
            if (lane == 0) unsafeAtomicAdd(&pp[0], 1.0f);
        }
    }
    __syncthreads();
    const int cmax = min(FB_CG, classes - gbase);
    float* gout = out + (size_t)gbase * ROWLEN;
    for (int i = tid; i < cmax * ROWLEN; i += FB_T) {
        const float vv = part[i];
        if (vv != 0.0f) unsafeAtomicAdd(&gout[i], vv);
    }
}

// ------------------------------------------------------------------ launch --
extern "C" void kernel_launch(void* const* d_in, const int* in_sizes, int n_in,
                              void* d_out, int out_size, void* d_ws, size_t ws_size,
                              hipStream_t stream)
{
    const float* X      = (const float*)d_in[0];
    const int*   labels = (const int*)d_in[1];
    float*       out    = (float*)d_out;

    const int N       = in_sizes[1];
    const int classes = out_size / ROWLEN;

    // ws layout: hist_part[HIST_B][1024] @0 (1 MiB) | off[1025] @1M |
    //            cursor[1024] @1M+8K | idx[N] @1M+16K
    const size_t HP_BYTES = (size_t)HIST_B * 1024 * 4;          // 1 MiB
    const size_t need = HP_BYTES + 16384 + (size_t)N * 4;
    const bool fast = (ws_size >= need) && (classes <= 1024);

    if (fast) {
        unsigned* hist_part = (unsigned*)d_ws;
        unsigned* off    = (unsigned*)((char*)d_ws + HP_BYTES);
        unsigned* cursor = (unsigned*)((char*)d_ws + HP_BYTES + 8192);
        unsigned* idx    = (unsigned*)((char*)d_ws + HP_BYTES + 16384);

        hist_kernel<<<HIST_B, HIST_T, 0, stream>>>(labels, N, classes,
                                                   hist_part);
        prefix_kernel<<<1, 1024, 0, stream>>>(hist_part, off, cursor, classes);
        const int sblocks = (N + SCAT_T * SCAT_IT - 1) / (SCAT_T * SCAT_IT);
        scatter_kernel<<<sblocks, SCAT_T, 0, stream>>>(labels, N, classes,
                                                       cursor, idx);
        accum_kernel<<<classes, AT, 0, stream>>>(X, idx, off, out);
    } else {
        hipMemsetAsync(d_out, 0, (size_t)out_size * sizeof(float), stream);
        const int groups = (classes + FB_CG - 1) / FB_CG;
        const int target_chunks = 32;
        int rpc = (N + target_chunks - 1) / target_chunks;
        const int batch = FB_W * 64;
        rpc = ((rpc + batch - 1) / batch) * batch;
        const int chunks = (N + rpc - 1) / rpc;
        dim3 grid(chunks, groups);
        fb_kernel<<<grid, FB_T, 0, stream>>>(X, labels, out, N, classes, rpc);
    }
}

// Round 8
// 245.353 us; speedup vs baseline: 1.0327x; 1.0327x over previous
//
#include <hip/hip_runtime.h>

// DistributionTracker: per-label scatter-add of [count | sum(X) | sum(X^2)]
// X: (N, 128) fp32, labels: (N,) int32, out: (classes, 257) fp32 row-major.
//
// Round-8 = round-5 revert (empirical best: 245.7 us).
//   k1 hist   : per-block LDS histogram -> per-block partials hp[block][1024]
//               (int4 label loads); also grid-stride zeroes d_out
//   k2 prefix : column-sum the 256 partials (coalesced, L2-hot) + scan
//   k3 scatter: per-block LDS hist + cursor base, row indices sorted by class
//   k4 accum  : one wave per class-quarter (SPLIT=4, 64-thr blocks, 16
//               waves/CU — measured optimum; 31 waves/CU regressed);
//               lane owns cols {2l,2l+1}; one dwordx2 (512B/wave) load per
//               row; 8 unroll-slot register accumulators; NO LDS/atomics in
//               hot loop; flush = 4 global f32 atomics/lane + count.
// Gather is pinned at ~5.2 TB/s: random permutation of 512B row-granules
// (same-class rows ~1000 apart -> isolated DRAM granules). Structural.
// Fallback: round-1 ballot-scan kernel (correct, slow) if ws too small.

constexpr int DIM    = 128;
constexpr int ROWLEN = 2 * DIM + 1;    // 257

constexpr int HIST_B = 256;
constexpr int HIST_T = 256;

// ---------------------------------------------------------------- binning --
__global__ __launch_bounds__(HIST_T)
void hist_kernel(const int* __restrict__ labels, int N, int classes,
                 unsigned* __restrict__ hist_part,   // [HIST_B][1024]
                 float* __restrict__ out, int out_total)
{
    // zero the output (disjoint writes; accum runs 3 dispatches later)
    for (int i = blockIdx.x * HIST_T + threadIdx.x; i < out_total;
         i += HIST_B * HIST_T) out[i] = 0.0f;

    __shared__ unsigned lh[1024];
    for (int i = threadIdx.x; i < 1024; i += HIST_T) lh[i] = 0;
    __syncthreads();

    const int gtid = blockIdx.x * HIST_T + threadIdx.x;
    const int gstr = HIST_B * HIST_T;
    const int N4   = N >> 2;
    const int4* l4 = (const int4*)labels;
    for (int i = gtid; i < N4; i += gstr) {
        const int4 v = l4[i];
        if ((unsigned)v.x < (unsigned)classes) atomicAdd(&lh[v.x], 1u);
        if ((unsigned)v.y < (unsigned)classes) atomicAdd(&lh[v.y], 1u);
        if ((unsigned)v.z < (unsigned)classes) atomicAdd(&lh[v.z], 1u);
        if ((unsigned)v.w < (unsigned)classes) atomicAdd(&lh[v.w], 1u);
    }
    for (int i = (N4 << 2) + gtid; i < N; i += gstr) {
        const unsigned l = (unsigned)labels[i];
        if (l < (unsigned)classes) atomicAdd(&lh[l], 1u);
    }
    __syncthreads();
    unsigned* hp = hist_part + (size_t)blockIdx.x * 1024;
    for (int i = threadIdx.x; i < 1024; i += HIST_T) hp[i] = lh[i];
}

__global__ __launch_bounds__(1024)
void prefix_kernel(const unsigned* __restrict__ hist_part,
                   unsigned* __restrict__ off,
                   unsigned* __restrict__ cursor, int classes)
{
    __shared__ unsigned s[1024];
    const int tid = threadIdx.x;
    unsigned a0 = 0, a1 = 0, a2 = 0, a3 = 0;
    for (int b = 0; b < HIST_B; b += 4) {               // coalesced across tid
        a0 += hist_part[(b + 0) * 1024 + tid];
        a1 += hist_part[(b + 1) * 1024 + tid];
        a2 += hist_part[(b + 2) * 1024 + tid];
        a3 += hist_part[(b + 3) * 1024 + tid];
    }
    s[tid] = (tid < classes) ? (a0 + a1 + a2 + a3) : 0u;
    __syncthreads();
    for (int d = 1; d < 1024; d <<= 1) {
        unsigned v = (tid >= d) ? s[tid - d] : 0u;
        __syncthreads();
        s[tid] += v;
        __syncthreads();
    }
    if (tid == 0) { off[0] = 0; cursor[0] = 0; }
    if (tid < classes) {
        off[tid + 1] = s[tid];
        if (tid > 0) cursor[tid] = s[tid - 1];
    }
}

constexpr int SCAT_T  = 256;
constexpr int SCAT_IT = 16;            // 4096 rows per block

__global__ __launch_bounds__(SCAT_T)
void scatter_kernel(const int* __restrict__ labels, int N, int classes,
                    unsigned* __restrict__ cursor,
                    unsigned* __restrict__ idx)
{
    __shared__ unsigned lh[1024], lbase[1024];
    const int tid  = threadIdx.x;
    const int tile = blockIdx.x * (SCAT_T * SCAT_IT);
    for (int i = tid; i < 1024; i += SCAT_T) lh[i] = 0;
    __syncthreads();

    int lab[SCAT_IT];
#pragma unroll
    for (int k = 0; k < SCAT_IT; ++k) {
        const int row = tile + k * SCAT_T + tid;
        lab[k] = -1;
        if (row < N) {
            const unsigned l = (unsigned)labels[row];
            if (l < (unsigned)classes) { lab[k] = (int)l; atomicAdd(&lh[l], 1u); }
        }
    }
    __syncthreads();
    for (int c = tid; c < classes; c += SCAT_T) {
        if (lh[c]) lbase[c] = atomicAdd(&cursor[c], lh[c]);
        lh[c] = 0;
    }
    __syncthreads();
#pragma unroll
    for (int k = 0; k < SCAT_IT; ++k) {
        if (lab[k] >= 0) {
            const unsigned l   = (unsigned)lab[k];
            const unsigned row = (unsigned)(tile + k * SCAT_T + tid);
            idx[lbase[l] + atomicAdd(&lh[l], 1u)] = row;
        }
    }
}

// ------------------------------------------------------------- accumulate --
constexpr int SPLIT = 4;               // waves per class
constexpr int U     = 8;               // rows in flight per wave

__global__ __launch_bounds__(64)
void accum_kernel(const float* __restrict__ X,
                  const unsigned* __restrict__ gidx,
                  const unsigned* __restrict__ off,
                  float* __restrict__ out)
{
    const int c = blockIdx.x / SPLIT;
    const int h = blockIdx.x % SPLIT;
    const unsigned s   = off[c];
    const unsigned cnt = off[c + 1] - s;
    if (cnt == 0) return;
    const unsigned s_h = s + (unsigned)(((unsigned long long)cnt * h) / SPLIT);
    const unsigned e_h = s + (unsigned)(((unsigned long long)cnt * (h + 1)) / SPLIT);
    if (s_h >= e_h) return;

    const int lane = threadIdx.x;

    float2 m[U], q[U];
#pragma unroll
    for (int u = 0; u < U; ++u) {
        m[u].x = m[u].y = 0.0f; q[u].x = q[u].y = 0.0f;
    }

    unsigned p = s_h;
    for (; p + U <= e_h; p += U) {
        const float2* Xr[U];
#pragma unroll
        for (int u = 0; u < U; ++u) {
            const unsigned r = __builtin_amdgcn_readfirstlane(gidx[p + u]);
            Xr[u] = (const float2*)(X + (size_t)r * DIM);
        }
#pragma unroll
        for (int u = 0; u < U; ++u) {
            const float2 x = Xr[u][lane];           // cols {2l, 2l+1}, 512B/wave
            m[u].x += x.x;                   m[u].y += x.y;
            q[u].x = fmaf(x.x, x.x, q[u].x); q[u].y = fmaf(x.y, x.y, q[u].y);
        }
    }
    for (; p < e_h; ++p) {
        const unsigned r = __builtin_amdgcn_readfirstlane(gidx[p]);
        const float2 x = ((const float2*)(X + (size_t)r * DIM))[lane];
        m[0].x += x.x;                   m[0].y += x.y;
        q[0].x = fmaf(x.x, x.x, q[0].x); q[0].y = fmaf(x.y, x.y, q[0].y);
    }

#pragma unroll
    for (int u = 1; u < U; ++u) {
        m[0].x += m[u].x; m[0].y += m[u].y;
        q[0].x += q[u].x; q[0].y += q[u].y;
    }

    float* po = out + (size_t)c * ROWLEN;
    unsafeAtomicAdd(po + 1   + 2 * lane, m[0].x);
    unsafeAtomicAdd(po + 2   + 2 * lane, m[0].y);
    unsafeAtomicAdd(po + 129 + 2 * lane, q[0].x);
    unsafeAtomicAdd(po + 130 + 2 * lane, q[0].y);
    if (lane == 0) unsafeAtomicAdd(po, (float)(e_h - s_h));
}

// ---------------------------------------------------- fallback (round 1) ---
constexpr int FB_T = 512;
constexpr int FB_W = FB_T / 64;
constexpr int FB_CG = 63;

__global__ __launch_bounds__(FB_T, 2)
void fb_kernel(const float* __restrict__ X, const int* __restrict__ labels,
               float* __restrict__ out, int N, int classes, int rpc)
{
    __shared__ float part[FB_CG * ROWLEN];
    const int tid = threadIdx.x, lane = tid & 63, wid = tid >> 6;
    const int gbase = blockIdx.y * FB_CG;
    for (int i = tid; i < FB_CG * ROWLEN; i += FB_T) part[i] = 0.0f;
    __syncthreads();
    const long long row0 = (long long)blockIdx.x * rpc;
    int rows = rpc;
    if (row0 + rows > N) rows = (int)((long long)N - row0);
    for (int base = wid * 64; base < rows; base += FB_W * 64) {
        const int nb = min(64, rows - base);
        int lab = -1;
        if (lane < nb) lab = labels[row0 + base + lane];
        const int lc = lab - gbase;
        const bool in = (lab >= 0) && (lc >= 0) && (lc < FB_CG) && (lab < classes);
        unsigned long long mask = __ballot(in);
        while (mask) {
            const int j = __ffsll((long long)mask) - 1;
            mask &= mask - 1;
            const int cc = __shfl(lc, j);
            const size_t ridx = (size_t)(row0 + base + j) * DIM;
            const float x0 = X[ridx + lane];
            const float x1 = X[ridx + lane + 64];
            float* pp = &part[cc * ROWLEN];
            unsafeAtomicAdd(&pp[1 + lane], x0);
            unsafeAtomicAdd(&pp[65 + lane], x1);
            unsafeAtomicAdd(&pp[129 + lane], x0 * x0);
            unsafeAtomicAdd(&pp[193 + lane], x1 * x1);
            if (lane == 0) unsafeAtomicAdd(&pp[0], 1.0f);
        }
    }
    __syncthreads();
    const int cmax = min(FB_CG, classes - gbase);
    float* gout = out + (size_t)gbase * ROWLEN;
    for (int i = tid; i < cmax * ROWLEN; i += FB_T) {
        const float vv = part[i];
        if (vv != 0.0f) unsafeAtomicAdd(&gout[i], vv);
    }
}

// ------------------------------------------------------------------ launch --
extern "C" void kernel_launch(void* const* d_in, const int* in_sizes, int n_in,
                              void* d_out, int out_size, void* d_ws, size_t ws_size,
                              hipStream_t stream)
{
    const float* X      = (const float*)d_in[0];
    const int*   labels = (const int*)d_in[1];
    float*       out    = (float*)d_out;

    const int N       = in_sizes[1];
    const int classes = out_size / ROWLEN;

    // ws layout: hist_part[256][1024] @0 (1 MiB) | off[1025] @1 MiB |
    //            cursor[1024] @1 MiB+8 KiB | idx[N] @1 MiB+16 KiB
    const size_t HP_BYTES = (size_t)HIST_B * 1024 * 4;          // 1 MiB
    const size_t need = HP_BYTES + 16384 + (size_t)N * 4;
    const bool fast = (ws_size >= need) && (classes <= 1024);

    if (fast) {
        unsigned* hist_part = (unsigned*)d_ws;
        unsigned* off    = (unsigned*)((char*)d_ws + HP_BYTES);
        unsigned* cursor = (unsigned*)((char*)d_ws + HP_BYTES + 8192);
        unsigned* idx    = (unsigned*)((char*)d_ws + HP_BYTES + 16384);

        hist_kernel<<<HIST_B, HIST_T, 0, stream>>>(labels, N, classes,
                                                   hist_part, out, out_size);
        prefix_kernel<<<1, 1024, 0, stream>>>(hist_part, off, cursor, classes);
        const int sblocks = (N + SCAT_T * SCAT_IT - 1) / (SCAT_T * SCAT_IT);
        scatter_kernel<<<sblocks, SCAT_T, 0, stream>>>(labels, N, classes,
                                                       cursor, idx);
        accum_kernel<<<classes * SPLIT, 64, 0, stream>>>(X, idx, off, out);
    } else {
        hipMemsetAsync(d_out, 0, (size_t)out_size * sizeof(float), stream);
        const int groups = (classes + FB_CG - 1) / FB_CG;
        const int target_chunks = 32;
        int rpc = (N + target_chunks - 1) / target_chunks;
        const int batch = FB_W * 64;
        rpc = ((rpc + batch - 1) / batch) * batch;
        const int chunks = (N + rpc - 1) / rpc;
        dim3 grid(chunks, groups);
        fb_kernel<<<grid, FB_T, 0, stream>>>(X, labels, out, N, classes, rpc);
    }
}